// Round 1
// baseline (86.781 us; speedup 1.0000x reference)
//
#include <hip/hip_runtime.h>

// MonarchEmbedding: out[t, kr*32+o] = (kr&1)==(k>>5) ? L[k,b1,kr>>1] * R[kr,k&31,o] : 0
// where v = x[t], k = v/786, b1 = v%786.
// Derivation: p[c]=(c%64)*16+c//64 (perfect_shuffle(64,1024)); BLd[v,col] nonzero
// iff col//16==k, so the einsum over b collapses to a single product. Exact fp32
// match to the reference (the other terms are exact zeros).

#define BL1 786
#define TOK_TOTAL (8 * 2048)

__global__ __launch_bounds__(256) void monarch_embed_kernel(
    const int* __restrict__ x,
    const float* __restrict__ L,   // [64, 786, 16]
    const float* __restrict__ R,   // [32, 32, 32]
    float4* __restrict__ out)      // [n_tok, 1024] viewed as [n_tok, 256] float4
{
    const int token = blockIdx.x;
    const int v  = x[token];           // in [0, 64*786)
    const int k  = v / BL1;            // compiler emits magic-mul
    const int b1 = v - k * BL1;

    const int t  = threadIdx.x;        // 0..255
    const int kr = t >> 3;             // output row kr = (4t)/32, 0..31
    const int o0 = (t & 7) << 2;       // output col within row, multiple of 4

    float4 val = make_float4(0.f, 0.f, 0.f, 0.f);
    if ((kr & 1) == (k >> 5)) {
        const float l = L[(k * BL1 + b1) * 16 + (kr >> 1)];
        const float4 r = *reinterpret_cast<const float4*>(
            R + ((kr << 5) + (k & 31)) * 32 + o0);
        val = make_float4(l * r.x, l * r.y, l * r.z, l * r.w);
    }
    out[(size_t)token * 256 + t] = val;
}

extern "C" void kernel_launch(void* const* d_in, const int* in_sizes, int n_in,
                              void* d_out, int out_size, void* d_ws, size_t ws_size,
                              hipStream_t stream) {
    const int*   x = (const int*)d_in[0];
    const float* L = (const float*)d_in[1];
    const float* R = (const float*)d_in[2];
    // d_in[3] = p, unused: closed form derived above for perfect_shuffle(64,1024).

    const int n_tok = in_sizes[0];     // 8*2048 = 16384
    monarch_embed_kernel<<<dim3(n_tok), dim3(256), 0, stream>>>(
        x, L, R, (float4*)d_out);
}

// Round 3
// 85.323 us; speedup vs baseline: 1.0171x; 1.0171x over previous
//
#include <hip/hip_runtime.h>

// MonarchEmbedding: out[t, kr*32+o] = (kr&1)==(k>>5) ? L[k,b1,kr>>1] * R[kr,k&31,o] : 0
// where v = x[t], k = v/786, and L[k,b1,kr>>1] = Lflat[v*16 + (kr>>1)].
// Derivation: p[c]=(c%64)*16+c//64 (perfect_shuffle(64,1024)); BLd[v,col] nonzero
// iff col//16==k, so the einsum over b collapses to a single product. Exact fp32
// match to the reference (the other terms are exact zeros).
//
// R1/R2: grid-stride restructure — 8 tokens/block, fully unrolled, so each
// thread has 8 independent 16B stores in flight (was 1 store per short-lived
// block). Write-once output -> nontemporal store. R2 fix: native ext_vector
// float4 (HIP_vector_type rejected by __builtin_nontemporal_store).

#define BL1 786
#define TOK_PER_BLOCK 8

typedef float vfloat4 __attribute__((ext_vector_type(4)));

__global__ __launch_bounds__(256) void monarch_embed_kernel(
    const int* __restrict__ x,
    const float* __restrict__ L,     // [64, 786, 16] flat
    const float* __restrict__ R,     // [32, 32, 32]  flat
    vfloat4* __restrict__ out)       // [n_tok, 1024] viewed as [n_tok, 256] vfloat4
{
    const int t  = threadIdx.x;        // 0..255
    const int kr = t >> 3;             // output row, 0..31
    const int o0 = (t & 7) << 2;       // col within row, multiple of 4
    const int base = blockIdx.x * TOK_PER_BLOCK;

#pragma unroll
    for (int i = 0; i < TOK_PER_BLOCK; ++i) {
        const int token = base + i;
        const int v = x[token];        // block-uniform -> s_load
        const int k = v / BL1;         // magic-mul

        vfloat4 val = (vfloat4)(0.f);
        if ((kr & 1) == (k >> 5)) {
            const float   l = L[v * 16 + (kr >> 1)];
            const vfloat4 r = *reinterpret_cast<const vfloat4*>(
                R + ((kr << 5) + (k & 31)) * 32 + o0);
            val = l * r;
        }
        __builtin_nontemporal_store(val, &out[(size_t)token * 256 + t]);
    }
}

extern "C" void kernel_launch(void* const* d_in, const int* in_sizes, int n_in,
                              void* d_out, int out_size, void* d_ws, size_t ws_size,
                              hipStream_t stream) {
    const int*   x = (const int*)d_in[0];
    const float* L = (const float*)d_in[1];
    const float* R = (const float*)d_in[2];
    // d_in[3] = p, unused: closed form derived above for perfect_shuffle(64,1024).

    const int n_tok  = in_sizes[0];              // 8*2048 = 16384
    const int blocks = n_tok / TOK_PER_BLOCK;    // 2048
    monarch_embed_kernel<<<dim3(blocks), dim3(256), 0, stream>>>(
        x, L, R, (vfloat4*)d_out);
}

// Round 4
// 84.049 us; speedup vs baseline: 1.0325x; 1.0152x over previous
//
#include <hip/hip_runtime.h>

// MonarchEmbedding: out[t, kr*32+o] = (kr&1)==(k>>5) ? L[k,b1,kr>>1] * R[kr,k&31,o] : 0
// where v = x[t], k = v/786, and L[k,b1,kr>>1] = Lflat[v*16 + (kr>>1)].
// Derivation: p[c]=(c%64)*16+c//64 (perfect_shuffle(64,1024)); BLd[v,col] nonzero
// iff col//16==k, so the einsum over b collapses to a single product. Exact fp32
// match to the reference (the other terms are exact zeros).
//
// R4: drop the nontemporal hint (suspected sc0/sc1 cache-bypass capping store BW
// at ~2.4 TB/s vs ~6 TB/s cached write-back). Hoist the 8 block-uniform x loads
// into a front phase so 8 independent store chains stay in flight per wave.

#define BL1 786
#define TOK_PER_BLOCK 8

typedef float vfloat4 __attribute__((ext_vector_type(4)));

__global__ __launch_bounds__(256) void monarch_embed_kernel(
    const int* __restrict__ x,
    const float* __restrict__ L,     // [64, 786, 16] flat
    const float* __restrict__ R,     // [32, 32, 32]  flat
    vfloat4* __restrict__ out)       // [n_tok, 1024] viewed as [n_tok, 256] vfloat4
{
    const int t  = threadIdx.x;        // 0..255
    const int kr = t >> 3;             // output row, 0..31
    const int o0 = (t & 7) << 2;       // col within row, multiple of 4
    const int base = blockIdx.x * TOK_PER_BLOCK;

    // Phase 1: all 8 block-uniform index loads issue up front (s_loads).
    int v[TOK_PER_BLOCK];
#pragma unroll
    for (int i = 0; i < TOK_PER_BLOCK; ++i) v[i] = x[base + i];

    // Phase 2: compute + store, 8 independent chains.
#pragma unroll
    for (int i = 0; i < TOK_PER_BLOCK; ++i) {
        const int k = v[i] / BL1;      // magic-mul

        vfloat4 val = (vfloat4)(0.f);
        if ((kr & 1) == (k >> 5)) {
            const float   l = L[v[i] * 16 + (kr >> 1)];
            const vfloat4 r = *reinterpret_cast<const vfloat4*>(
                R + ((kr << 5) + (k & 31)) * 32 + o0);
            val = l * r;
        }
        out[(size_t)(base + i) * 256 + t] = val;
    }
}

extern "C" void kernel_launch(void* const* d_in, const int* in_sizes, int n_in,
                              void* d_out, int out_size, void* d_ws, size_t ws_size,
                              hipStream_t stream) {
    const int*   x = (const int*)d_in[0];
    const float* L = (const float*)d_in[1];
    const float* R = (const float*)d_in[2];
    // d_in[3] = p, unused: closed form derived above for perfect_shuffle(64,1024).

    const int n_tok  = in_sizes[0];              // 8*2048 = 16384
    const int blocks = n_tok / TOK_PER_BLOCK;    // 2048
    monarch_embed_kernel<<<dim3(blocks), dim3(256), 0, stream>>>(
        x, L, R, (vfloat4*)d_out);
}